// Round 1
// baseline (2000.860 us; speedup 1.0000x reference)
//
#include <hip/hip_runtime.h>
#include <math.h>

#define NA 512
#define NN (NA*NA)
#define COULOMB 14.399645478425668f
#define SQRT_PI 1.7724538509055160273f

__device__ __forceinline__ float rl(float x, int lane) {
    return __int_as_float(__builtin_amdgcn_readlane(__float_as_int(x), lane));
}

// ---------------------------------------------------------------- K1: per-atom
__global__ void k_pre(const float* __restrict__ feats, const float* __restrict__ w,
                      const int* __restrict__ type, const float* __restrict__ hard,
                      const float* __restrict__ sigma,
                      float* __restrict__ chi, float* __restrict__ diag,
                      float* __restrict__ sigA, int N) {
    __shared__ float wl[64];
    int tid = threadIdx.x;
    if (tid < 64) wl[tid] = w[tid];
    __syncthreads();
    int i = blockIdx.x * 256 + tid;
    if (i >= N) return;
    const float4* fp = (const float4*)(feats + (size_t)i * 64);
    float acc = 0.f;
#pragma unroll
    for (int q = 0; q < 16; q++) {
        float4 v = fp[q];
        acc += v.x * wl[4*q] + v.y * wl[4*q+1] + v.z * wl[4*q+2] + v.w * wl[4*q+3];
    }
    chi[i] = acc;
    int t = type[i];
    float s = sigma[t];
    float h = hard[t];
    sigA[i] = s;
    diag[i] = h * h + COULOMB / (SQRT_PI * s);
}

// ---------------------------------------------------------------- K2: build C
__global__ void k_build(const float* __restrict__ pos, const float* __restrict__ sigA,
                        const float* __restrict__ diagA, float* __restrict__ C) {
    int b = blockIdx.y;
    int tile = blockIdx.x;
    int ti = tile >> 3, tj = tile & 7;
    __shared__ float pIx[64], pIy[64], pIz[64], sI2[64];
    __shared__ float pJx[64], pJy[64], pJz[64], sJ2[64];
    int tid = threadIdx.x;
    int aI = b * NA + ti * 64;
    int aJ = b * NA + tj * 64;
    if (tid < 64) {
        pIx[tid] = pos[(size_t)(aI + tid) * 3 + 0];
        pIy[tid] = pos[(size_t)(aI + tid) * 3 + 1];
        pIz[tid] = pos[(size_t)(aI + tid) * 3 + 2];
        float s = sigA[aI + tid]; sI2[tid] = s * s;
    } else if (tid < 128) {
        int u = tid - 64;
        pJx[u] = pos[(size_t)(aJ + u) * 3 + 0];
        pJy[u] = pos[(size_t)(aJ + u) * 3 + 1];
        pJz[u] = pos[(size_t)(aJ + u) * 3 + 2];
        float s = sigA[aJ + u]; sJ2[u] = s * s;
    }
    __syncthreads();
    float* Cb = C + (size_t)b * NN;
    int c = tid & 63;
    int r0 = tid >> 6;
#pragma unroll
    for (int s = 0; s < 16; s++) {
        int r = r0 + 4 * s;
        float val;
        if (ti == tj && r == c) {
            val = diagA[aI + r];
        } else {
            float dx = pIx[r] - pJx[c];
            float dy = pIy[r] - pJy[c];
            float dz = pIz[r] - pJz[c];
            float d2 = dx * dx + dy * dy + dz * dz;
            float rinv = rsqrtf(d2);
            float d = d2 * rinv;
            float arg = d * rsqrtf(2.f * (sI2[r] + sJ2[c]));
            val = COULOMB * erff(arg) * rinv;
        }
        Cb[(size_t)(ti * 64 + r) * NA + tj * 64 + c] = val;
    }
}

// ------------------------------------------- K3: diag factor + panel trsm (step j)
__global__ void __launch_bounds__(512) k_panel(float* __restrict__ C, const int j) {
    int b = blockIdx.x;
    float* Cb = C + (size_t)b * NN;
    const int jb = j * 64;
    const int m = NA - jb - 64;
    __shared__ float D[64 * 65];
    __shared__ float DT[64 * 64];   // strict lower of Ljj, zeros elsewhere (f4-aligned)
    __shared__ float invd[64];      // 1/L[k][k]
    int tid = threadIdx.x;

    // cooperative load of diag tile (full rows; upper half unused by factor)
#pragma unroll
    for (int e = 0; e < 8; e++) {
        int f = e * 512 + tid;
        int row = f >> 6, cc = f & 63;
        D[row * 65 + cc] = Cb[(size_t)(jb + row) * NA + jb + cc];
    }
    // preload panel row into registers (overlaps with factor)
    float rv[64];
    int r = tid - 64;
    if (r >= 0 && r < m) {
        const float4* rp = (const float4*)(Cb + (size_t)(jb + 64 + r) * NA + jb);
#pragma unroll
        for (int q = 0; q < 16; q++) {
            float4 v = rp[q];
            rv[4*q] = v.x; rv[4*q+1] = v.y; rv[4*q+2] = v.z; rv[4*q+3] = v.w;
        }
    }
    __syncthreads();

    // wave 0: register-resident symmetric Gaussian elimination (no barriers)
    if (tid < 64) {
        const int t = tid;
        float cl[64];
#pragma unroll
        for (int i = 0; i < 64; i++) cl[i] = (i >= t) ? D[i * 65 + t] : D[t * 65 + i];
#pragma unroll
        for (int k = 0; k < 64; k++) {
            float pivot = rl(cl[k], k);
            float invp = 1.0f / pivot;
            float factor = (t > k) ? (cl[k] * invp) : 0.0f;
#pragma unroll
            for (int i = k + 1; i < 64; i++) {
                float bc = rl(cl[i], k);
                cl[i] -= bc * factor;
            }
        }
        float rs = 1.0f / sqrtf(cl[t]);
        invd[t] = rs;
#pragma unroll
        for (int i = 0; i < 64; i++)
            if (i >= t) D[i * 65 + t] = cl[i] * rs;
    }
    __syncthreads();

    // write L tile (lower) to global; build DT (strict lower, zero-padded)
#pragma unroll
    for (int e = 0; e < 8; e++) {
        int f = e * 512 + tid;
        int row = f >> 6, cc = f & 63;
        float val = D[row * 65 + cc];
        if (cc <= row) Cb[(size_t)(jb + row) * NA + jb + cc] = val;
        DT[row * 64 + cc] = (cc < row) ? val : 0.f;
    }
    __syncthreads();

    // row-owned trsm: L21 = A21 * Ljj^-T ; Ljj read as uniform f4 broadcasts
    if (r >= 0 && r < m) {
#pragma unroll
        for (int k = 0; k < 64; k++) {
            float acc = rv[k];
            const float4* Lr = (const float4*)(DT + k * 64);
            const int k4 = k >> 2;
#pragma unroll
            for (int t4 = 0; t4 < k4; t4++) {
                float4 Lv = Lr[t4];
                acc -= Lv.x * rv[4*t4] + Lv.y * rv[4*t4+1] + Lv.z * rv[4*t4+2] + Lv.w * rv[4*t4+3];
            }
#pragma unroll
            for (int tt = k4 * 4; tt < k; tt++) acc -= DT[k * 64 + tt] * rv[tt];
            rv[k] = acc * invd[k];
        }
        float4* rp = (float4*)(Cb + (size_t)(jb + 64 + r) * NA + jb);
#pragma unroll
        for (int q = 0; q < 16; q++) {
            float4 v;
            v.x = rv[4*q]; v.y = rv[4*q+1]; v.z = rv[4*q+2]; v.w = rv[4*q+3];
            rp[q] = v;
        }
    }
}

// ------------------------------------------- K4: trailing update (step j), lower only
__global__ void __launch_bounds__(256) k_trail(float* __restrict__ C, const int j) {
    int b = blockIdx.y;
    float* Cb = C + (size_t)b * NN;
    const int jb = j * 64;
    const int m = NA - jb - 64;
    // decode lower-tri supertile index -> (RI, RJ)
    int t = blockIdx.x;
    int RI = 0;
    while (t >= RI + 1) { t -= RI + 1; RI++; }
    const int RJ = t;
    const int RB = RI * 128, CB = RJ * 128;
    const int vr = min(128, m - RB);
    const int vc = min(128, m - CB);

    __shared__ float4 LI[128 * 8];
    __shared__ float4 LJ[128 * 8];
    int tid = threadIdx.x;
    int rg = tid >> 4, cg = tid & 15;
    float acc[8][8];
#pragma unroll
    for (int a = 0; a < 8; a++)
#pragma unroll
        for (int bq = 0; bq < 8; bq++) acc[a][bq] = 0.f;

    const float* Pan = Cb + (size_t)(jb + 64) * NA + jb;   // panel: row r -> Pan[r*NA + k]

    for (int kh = 0; kh < 2; kh++) {
        __syncthreads();
#pragma unroll
        for (int e = 0; e < 4; e++) {
            int f = e * 256 + tid;     // 0..1023 = 128 rows x 8 slots
            int row = f >> 3, s = f & 7;
            int slot = (s + (row >> 3)) & 7;
            float4 v = make_float4(0.f, 0.f, 0.f, 0.f);
            if (row < vr) v = *(const float4*)(Pan + (size_t)(RB + row) * NA + kh * 32 + s * 4);
            LI[row * 8 + slot] = v;
            if (RI != RJ) {
                float4 wv = make_float4(0.f, 0.f, 0.f, 0.f);
                if (row < vc) wv = *(const float4*)(Pan + (size_t)(CB + row) * NA + kh * 32 + s * 4);
                LJ[row * 8 + slot] = wv;
            }
        }
        __syncthreads();
        const float4* LJp = (RI != RJ) ? LJ : LI;
#pragma unroll
        for (int k4 = 0; k4 < 8; k4++) {
            float4 ai[8], bj[8];
#pragma unroll
            for (int rr = 0; rr < 8; rr++) ai[rr] = LI[(rg * 8 + rr) * 8 + ((k4 + rg) & 7)];
#pragma unroll
            for (int cc = 0; cc < 8; cc++) bj[cc] = LJp[(cg * 8 + cc) * 8 + ((k4 + cg) & 7)];
#pragma unroll
            for (int rr = 0; rr < 8; rr++)
#pragma unroll
                for (int cc = 0; cc < 8; cc++)
                    acc[rr][cc] += ai[rr].x * bj[cc].x + ai[rr].y * bj[cc].y
                                 + ai[rr].z * bj[cc].z + ai[rr].w * bj[cc].w;
        }
    }

    const int GRB = jb + 64 + RB, GCB = jb + 64 + CB;
    if (RI != RJ) {
#pragma unroll
        for (int rr = 0; rr < 8; rr++) {
            int row = rg * 8 + rr;
            if (row < vr && cg * 8 < vc) {
                float* rp = Cb + (size_t)(GRB + row) * NA + GCB + cg * 8;
                float4 v0 = *(float4*)rp;
                v0.x -= acc[rr][0]; v0.y -= acc[rr][1]; v0.z -= acc[rr][2]; v0.w -= acc[rr][3];
                *(float4*)rp = v0;
                float4 v1 = *(float4*)(rp + 4);
                v1.x -= acc[rr][4]; v1.y -= acc[rr][5]; v1.z -= acc[rr][6]; v1.w -= acc[rr][7];
                *(float4*)(rp + 4) = v1;
            }
        }
    } else {
#pragma unroll
        for (int rr = 0; rr < 8; rr++) {
            int row = rg * 8 + rr;
            if (row < vr) {
                int gr = GRB + row;
#pragma unroll
                for (int cc = 0; cc < 8; cc++) {
                    int col = cg * 8 + cc;
                    if (col < vc && gr >= GCB + col) {
                        float* p = Cb + (size_t)gr * NA + GCB + col;
                        *p -= acc[rr][cc];
                    }
                }
            }
        }
    }
}

// ------------------------------------------- K5: solves + mu + q + energy
__global__ void __launch_bounds__(512) k_solve(const float* __restrict__ C,
                                               const float* __restrict__ chiA,
                                               const float* __restrict__ diagA,
                                               const float* __restrict__ Qtot,
                                               float* __restrict__ out, int B) {
    int b = blockIdx.x;
    const float* Cb = C + (size_t)b * NN;
    int tid = threadIdx.x;
    __shared__ float D[64 * 65];
    __shared__ float v1[NA], v2[NA];
    __shared__ float tv1[64], tv2[64];
    __shared__ float pb[2][8][64];
    __shared__ float qs[NA];
    __shared__ float red[16];
    __shared__ float muS;

    v1[tid] = chiA[b * NA + tid];   // RHS1 = chi  (x1 = C^-1 chi)
    v2[tid] = 1.0f;                 // RHS2 = ones (x2 = C^-1 1)

    // -------- forward: y = L^-1 r (in place in v1/v2)
    for (int j = 0; j < 8; j++) {
        int jb = j * 64;
        __syncthreads();
#pragma unroll
        for (int e = 0; e < 8; e++) {
            int f = e * 512 + tid;
            int row = f >> 6, cc = f & 63;
            D[row * 65 + cc] = Cb[(size_t)(jb + row) * NA + jb + cc];
        }
        int i = tid >> 3, l8 = tid & 7;
        float pa1 = 0.f, pa2 = 0.f;
        for (int cx = l8; cx < jb; cx += 8) {
            float Lv = Cb[(size_t)(jb + i) * NA + cx];
            pa1 += Lv * v1[cx]; pa2 += Lv * v2[cx];
        }
        pa1 += __shfl_xor(pa1, 1); pa2 += __shfl_xor(pa2, 1);
        pa1 += __shfl_xor(pa1, 2); pa2 += __shfl_xor(pa2, 2);
        pa1 += __shfl_xor(pa1, 4); pa2 += __shfl_xor(pa2, 4);
        if (l8 == 0) { tv1[i] = v1[jb + i] - pa1; tv2[i] = v2[jb + i] - pa2; }
        __syncthreads();
        if (tid < 128) {
            int lane = tid & 63;
            float* vv = (tid < 64) ? v1 : v2;
            const float* tv = (tid < 64) ? tv1 : tv2;
            float val = tv[lane];
            float idg = 1.0f / D[lane * 65 + lane];
#pragma unroll
            for (int k = 0; k < 64; k++) {
                float yk = rl(val, k) * rl(idg, k);
                if (lane == k) vv[jb + k] = yk;
                float lv = (lane > k) ? D[lane * 65 + k] : 0.f;
                val -= lv * yk;
            }
        }
    }

    // -------- backward: x = L^-T y (in place)
    for (int j = 7; j >= 0; j--) {
        int jb = j * 64;
        __syncthreads();
#pragma unroll
        for (int e = 0; e < 8; e++) {
            int f = e * 512 + tid;
            int row = f >> 6, cc = f & 63;
            D[row * 65 + cc] = Cb[(size_t)(jb + row) * NA + jb + cc];
        }
        int trp = tid >> 6, i2 = tid & 63;
        float px1 = 0.f, px2 = 0.f;
        for (int gt = jb + 64 + trp; gt < NA; gt += 8) {
            float Lv = Cb[(size_t)gt * NA + jb + i2];
            px1 += Lv * v1[gt]; px2 += Lv * v2[gt];
        }
        pb[0][trp][i2] = px1; pb[1][trp][i2] = px2;
        __syncthreads();
        if (tid < 64) {
            float s = 0.f;
#pragma unroll
            for (int tr = 0; tr < 8; tr++) s += pb[0][tr][tid];
            tv1[tid] = v1[jb + tid] - s;
        } else if (tid < 128) {
            int l = tid - 64;
            float s = 0.f;
#pragma unroll
            for (int tr = 0; tr < 8; tr++) s += pb[1][tr][l];
            tv2[l] = v2[jb + l] - s;
        }
        __syncthreads();
        if (tid < 128) {
            int lane = tid & 63;
            float* vv = (tid < 64) ? v1 : v2;
            const float* tv = (tid < 64) ? tv1 : tv2;
            float val = tv[lane];
            float idg = 1.0f / D[lane * 65 + lane];
#pragma unroll
            for (int k = 63; k >= 0; k--) {
                float xk = rl(val, k) * rl(idg, k);
                if (lane == k) vv[jb + k] = xk;
                float lv = (lane < k) ? D[k * 65 + lane] : 0.f;
                val -= lv * xk;
            }
        }
    }
    __syncthreads();

    // -------- mu and q
    float s1p = v1[tid], s2p = v2[tid];
#pragma unroll
    for (int off = 1; off < 64; off <<= 1) {
        s1p += __shfl_xor(s1p, off);
        s2p += __shfl_xor(s2p, off);
    }
    if ((tid & 63) == 0) { red[tid >> 6] = s1p; red[8 + (tid >> 6)] = s2p; }
    __syncthreads();
    if (tid == 0) {
        float s1 = 0.f, s2 = 0.f;
#pragma unroll
        for (int wv = 0; wv < 8; wv++) { s1 += red[wv]; s2 += red[8 + wv]; }
        muS = -(Qtot[b] + s1) / s2;
    }
    __syncthreads();
    float mu = muS;
    float qv = -v1[tid] - mu * v2[tid];
    qs[tid] = qv;
    out[B + (size_t)b * NA + tid] = qv;
    __syncthreads();

    // -------- energy: strict upper of C is pristine (K2 values)
    float eacc = (0.5f * diagA[b * NA + tid] * qv + chiA[b * NA + tid]) * qv;
#pragma unroll 4
    for (int i = 0; i < NA - 1; i++) {
        int jj = i + 1 + tid;
        if (jj < NA) eacc += Cb[(size_t)i * NA + jj] * qs[i] * qs[jj];
    }
#pragma unroll
    for (int off = 1; off < 64; off <<= 1) eacc += __shfl_xor(eacc, off);
    __syncthreads();
    if ((tid & 63) == 0) red[tid >> 6] = eacc;
    __syncthreads();
    if (tid == 0) {
        float e = 0.f;
#pragma unroll
        for (int wv = 0; wv < 8; wv++) e += red[wv];
        out[b] = e;
    }
}

// ---------------------------------------------------------------- host launch
extern "C" void kernel_launch(void* const* d_in, const int* in_sizes, int n_in,
                              void* d_out, int out_size, void* d_ws, size_t ws_size,
                              hipStream_t stream) {
    const int B = in_sizes[3];          // 128 molecules
    const int N = in_sizes[2];          // 65536 atoms
    const float* feats = (const float*)d_in[0];
    const float* pos   = (const float*)d_in[1];
    const int*   type  = (const int*)d_in[2];
    const float* Qt    = (const float*)d_in[3];
    const float* w     = (const float*)d_in[4];
    const float* hard  = (const float*)d_in[5];
    const float* sig   = (const float*)d_in[6];
    float* out = (float*)d_out;
    float* ws  = (float*)d_ws;

    float* C    = ws;                       // B * 512 * 512
    float* chi  = ws + (size_t)B * NN;      // N
    float* diag = chi + N;                  // N
    float* sigA = diag + N;                 // N

    k_pre<<<(N + 255) / 256, 256, 0, stream>>>(feats, w, type, hard, sig, chi, diag, sigA, N);
    k_build<<<dim3(64, B), 256, 0, stream>>>(pos, sigA, diag, C);

    static const int tilesJ[7] = {10, 6, 6, 3, 3, 1, 1};
    for (int j = 0; j < 8; j++) {
        k_panel<<<B, 512, 0, stream>>>(C, j);
        if (j < 7) k_trail<<<dim3(tilesJ[j], B), 256, 0, stream>>>(C, j);
    }
    k_solve<<<B, 512, 0, stream>>>(C, chi, diag, Qt, out, B);
}